// Round 10
// baseline (157.402 us; speedup 1.0000x reference)
//
#include <hip/hip_runtime.h>
#include <hip/hip_bf16.h>

// ---------------------------------------------------------------------------
// GATConv (PyG-style, H=2 heads, C=64, concat=False -> head mean) on gfx950.
// Phases:
//   1. k_mega1  : [blocks 0..ngemm) h = x@W via bf16 MFMA 16x16x32; a_s/a_d
//                 from fp32 MFMA accs via LDS [64][4] atomic contraction.
//                 [blocks ngemm..) per-chunk LDS histogram (k_bhist) -- the
//                 two phases are independent; fusing overlaps MFMA with the
//                 edge-list stream and saves launches.
//   2. k_bscan/k_bbase/k_binsert/k_bucket: CSR build (two-level counting
//                 sort, no global atomics), as R7.
//   3. k_aggr   : TWO dst nodes per wave, pipelined: stage both nodes'
//                 {voff,w0,w1} (independent load chains overlap), then gather
//                 both. Head-split LDS broadcast (2-way = free); 1 uint4 = 2
//                 edges = full 256B h row per wave instr; 8 gathers in flight.
// ---------------------------------------------------------------------------

#define NBLK 256   // edge chunks (= threads in k_bscan)
#define TH 512     // threads for binsert
#define BSH 7      // bucket = dst >> 7
#define BSZ 128    // nodes per bucket
#define MAXBUCK 512
#define PLCAP 8192 // k_bucket LDS pair capacity (32 KB); avg bucket ~4224

typedef __attribute__((ext_vector_type(8))) short bf16x8;
typedef __attribute__((ext_vector_type(4))) float f32x4;

__device__ __forceinline__ ushort f2bf(float f) {
  __hip_bfloat16 b = __float2bfloat16(f);
  union { __hip_bfloat16 b; ushort u; } cv; cv.b = b; return cv.u;
}
__device__ __forceinline__ uint pk2(float a, float b) {
  return (uint)f2bf(a) | ((uint)f2bf(b) << 16);
}
__device__ __forceinline__ float leaky02(float v) {
  return fmaxf(v, 0.2f * v);  // slope 0.2 leaky relu (valid for both signs)
}

// ---- fused GEMM (+logits) and edge-histogram mega-kernel ----
__global__ __launch_bounds__(256) void k_mega1(
    const float* __restrict__ x, const float* __restrict__ W,
    const float* __restrict__ att_s, const float* __restrict__ att_d,
    __hip_bfloat162* __restrict__ h2, float* __restrict__ a_s,
    float* __restrict__ a_d, int Nn, const int* __restrict__ dst,
    int* __restrict__ bhist, int E, int nbuck, int chunkE, int ngemm) {
  __shared__ char smem[64 * 128 * 2 + 64 * 4 * 4];  // 16KB x-tile + 1KB asd
  if ((int)blockIdx.x >= ngemm) {
    // ---------------- histogram branch ----------------
    int* hl = (int*)smem;
    const int bb = (int)blockIdx.x - ngemm;
    for (int i = threadIdx.x; i < nbuck; i += 256) hl[i] = 0;
    __syncthreads();
    const int s = bb * chunkE;
    const int e = (s + chunkE < E) ? s + chunkE : E;
    for (int i = s + threadIdx.x; i < e; i += 256)
      atomicAdd(&hl[dst[i] >> BSH], 1);
    __syncthreads();
    for (int b = threadIdx.x; b < nbuck; b += 256)
      bhist[b * NBLK + bb] = hl[b];
    return;
  }
  // ---------------- GEMM branch ----------------
  ushort* Al = (ushort*)smem;                  // XOR-swizzled bf16 x-tile
  float(*asd)[4] = (float(*)[4])(smem + 64 * 128 * 2);  // [64][4]
  char* lb = (char*)Al;
  const int wave = threadIdx.x >> 6;
  const int lane = threadIdx.x & 63;
  const int row0 = blockIdx.x * 64;
  const int l15 = lane & 15;
  const int kb = (lane >> 4) * 8;

  ((float*)asd)[threadIdx.x] = 0.f;  // zero asd (256 floats)

  // stage x tile: fp32 -> bf16 LDS, swizzled
  {
    const int t = threadIdx.x;
    const int srow = t >> 2, q = t & 3;
    int gr = row0 + srow; gr = (gr < Nn) ? gr : (Nn - 1);
    const float4* xr = (const float4*)&x[(size_t)gr * 128 + q * 32];
#pragma unroll
    for (int i = 0; i < 4; ++i) {
      float4 v0 = xr[2 * i], v1 = xr[2 * i + 1];
      uint4 w;
      w.x = pk2(v0.x, v0.y); w.y = pk2(v0.z, v0.w);
      w.z = pk2(v1.x, v1.y); w.w = pk2(v1.z, v1.w);
      int byte = srow * 256 + ((q * 64 + i * 16) ^ ((srow & 7) << 4));
      *(uint4*)(lb + byte) = w;
    }
  }
  // B fragments (W) in registers: 2 col-tiles x 4 k-steps
  bf16x8 bfr[2][4];
#pragma unroll
  for (int c = 0; c < 2; ++c) {
#pragma unroll
    for (int ks = 0; ks < 4; ++ks) {
      const float* wp = &W[(ks * 32 + kb) * 128 + wave * 32 + c * 16 + l15];
      union { bf16x8 v; ushort u[8]; } t;
#pragma unroll
      for (int j = 0; j < 8; ++j) t.u[j] = f2bf(wp[j * 128]);
      bfr[c][ks] = t.v;
    }
  }
  // att coefficients for this thread's two columns
  const int col0 = wave * 32 + l15, col1 = col0 + 16;
  const float as0c = att_s[col0], as1c = att_s[col1];
  const float ad0c = att_d[col0], ad1c = att_d[col1];
  const int head = wave >> 1;

  __syncthreads();

  f32x4 acc[4][2];
#pragma unroll
  for (int r = 0; r < 4; ++r) {
    acc[r][0] = (f32x4){0.f, 0.f, 0.f, 0.f};
    acc[r][1] = (f32x4){0.f, 0.f, 0.f, 0.f};
  }
#pragma unroll
  for (int ks = 0; ks < 4; ++ks) {
    bf16x8 af[4];
#pragma unroll
    for (int r = 0; r < 4; ++r) {
      int row = r * 16 + l15;
      int byte = row * 256 + ((ks * 64 + (lane >> 4) * 16) ^ ((row & 7) << 4));
      uint4 v = *(const uint4*)(lb + byte);
      union { uint4 q; bf16x8 v; } cv; cv.q = v;
      af[r] = cv.v;
    }
#pragma unroll
    for (int r = 0; r < 4; ++r) {
      acc[r][0] = __builtin_amdgcn_mfma_f32_16x16x32_bf16(af[r], bfr[0][ks],
                                                          acc[r][0], 0, 0, 0);
      acc[r][1] = __builtin_amdgcn_mfma_f32_16x16x32_bf16(af[r], bfr[1][ks],
                                                          acc[r][1], 0, 0, 0);
    }
  }

  // store h (bf16) + accumulate logit contributions into asd
  ushort* hs = (ushort*)h2;
  const int rbase = (lane >> 4) * 4;
#pragma unroll
  for (int r = 0; r < 4; ++r) {
#pragma unroll
    for (int i = 0; i < 4; ++i) {
      const int lrow = r * 16 + rbase + i;
      const int grow = row0 + lrow;
      const float h0 = acc[r][0][i], h1 = acc[r][1][i];
      if (grow < Nn) {
        hs[(size_t)grow * 128 + col0] = f2bf(h0);
        hs[(size_t)grow * 128 + col1] = f2bf(h1);
      }
      atomicAdd(&asd[lrow][head], fmaf(h0, as0c, h1 * as1c));
      atomicAdd(&asd[lrow][2 + head], fmaf(h0, ad0c, h1 * ad1c));
    }
  }
  __syncthreads();
  if (threadIdx.x < 64) {
    const int grow = row0 + threadIdx.x;
    if (grow < Nn) {
      *(float2*)&a_s[grow * 2] = make_float2(asd[threadIdx.x][0], asd[threadIdx.x][1]);
      *(float2*)&a_d[grow * 2] = make_float2(asd[threadIdx.x][2], asd[threadIdx.x][3]);
    }
  }
}

// per bucket: exclusive scan over chunks -> raw cursors; write bucket total
__global__ __launch_bounds__(NBLK) void k_bscan(const int* __restrict__ bhist,
                                                int* __restrict__ cursors,
                                                int* __restrict__ totals,
                                                int nbuck) {
  __shared__ int tmp[NBLK];
  const int b = blockIdx.x;
  const int t = threadIdx.x;
  const int v = bhist[b * NBLK + t];
  tmp[t] = v;
  __syncthreads();
  for (int d = 1; d < NBLK; d <<= 1) {
    int add = (t >= d) ? tmp[t - d] : 0;
    __syncthreads();
    tmp[t] += add;
    __syncthreads();
  }
  cursors[t * nbuck + b] = tmp[t] - v;  // raw (no base)
  if (t == NBLK - 1) totals[b] = tmp[t];
}

// exclusive scan of bucket totals -> bases[0..nbuck]
__global__ __launch_bounds__(MAXBUCK) void k_bbase(const int* __restrict__ totals,
                                                   int* __restrict__ bases,
                                                   int nbuck) {
  __shared__ int tmp[MAXBUCK];
  const int t = threadIdx.x;
  const int v = (t < nbuck) ? totals[t] : 0;
  tmp[t] = v;
  __syncthreads();
  for (int d = 1; d < MAXBUCK; d <<= 1) {
    int add = (t >= d) ? tmp[t - d] : 0;
    __syncthreads();
    tmp[t] += add;
    __syncthreads();
  }
  if (t < nbuck) bases[t] = tmp[t] - v;
  if (t == nbuck - 1) bases[nbuck] = tmp[t];
}

// scatter packed (local_dst<<16 | src) into bucket-grouped pairs array
__global__ __launch_bounds__(TH) void k_binsert(
    const int* __restrict__ src, const int* __restrict__ dst,
    const int* __restrict__ cursors, const int* __restrict__ bases,
    int* __restrict__ pairs, int E, int nbuck, int chunk) {
  __shared__ int cur[MAXBUCK];
  for (int i = threadIdx.x; i < nbuck; i += TH)
    cur[i] = cursors[blockIdx.x * nbuck + i] + bases[i];
  __syncthreads();
  const int s = blockIdx.x * chunk;
  const int e = (s + chunk < E) ? s + chunk : E;
  for (int i = s + threadIdx.x; i < e; i += TH) {
    const int d = dst[i];
    const int b = d >> BSH;
    const int p = atomicAdd(&cur[b], 1);
    pairs[p] = ((d & (BSZ - 1)) << 16) | src[i];
  }
}

// per bucket: single-pass (pairs staged in LDS): count+scan -> off/cnt, then
// LDS-sourced scatter into csr. Fallback to two global passes if oversized.
__global__ __launch_bounds__(256) void k_bucket(
    const int* __restrict__ pairs, const int* __restrict__ bases,
    int* __restrict__ off, int* __restrict__ cnt, int* __restrict__ csr,
    int Nn) {
  __shared__ int pl[PLCAP];  // 32 KB
  __shared__ int cl[BSZ];
  __shared__ int tmp[BSZ];
  __shared__ int cu[BSZ];
  const int b = blockIdx.x;
  const int t = threadIdx.x;
  const int n0 = b << BSH;
  if (t < BSZ) cl[t] = 0;
  __syncthreads();
  const int s = bases[b], e = bases[b + 1];
  const int len = e - s;
  const bool fit = (len <= PLCAP);
  if (fit) {
    for (int i = t; i < len; i += 256) {
      int pv = pairs[s + i];
      pl[i] = pv;
      atomicAdd(&cl[pv >> 16], 1);
    }
  } else {
    for (int i = s + t; i < e; i += 256) atomicAdd(&cl[pairs[i] >> 16], 1);
  }
  __syncthreads();
  int v = 0;
  if (t < BSZ) { v = cl[t]; tmp[t] = v; }
  __syncthreads();
  for (int d = 1; d < BSZ; d <<= 1) {
    int add = (t < BSZ && t >= d) ? tmp[t - d] : 0;
    __syncthreads();
    if (t < BSZ) tmp[t] += add;
    __syncthreads();
  }
  if (t < BSZ) {
    const int excl = tmp[t] - v;
    cu[t] = s + excl;
    const int node = n0 + t;
    if (node < Nn) { off[node] = s + excl; cnt[node] = v; }
  }
  __syncthreads();
  if (fit) {
    for (int i = t; i < len; i += 256) {
      const int pv = pl[i];
      const int p = atomicAdd(&cu[pv >> 16], 1);
      csr[p] = pv & 0xffff;
    }
  } else {
    for (int i = s + t; i < e; i += 256) {
      const int pv = pairs[i];
      const int p = atomicAdd(&cu[pv >> 16], 1);
      csr[p] = pv & 0xffff;
    }
  }
}

// ---- k_aggr helpers ----
__device__ __forceinline__ void stage_chunk(
    const int* __restrict__ csr, const float* __restrict__ a_s, int o,
    int cbase, int rem, float2 ad2, int lane, uint2* __restrict__ rowA,
    uint2* __restrict__ rowB, float& swA, float& swB) {
  uint voff = 0; float w0 = 0.f, w1 = 0.f;
  if (lane < rem) {
    int sl = csr[o + cbase + lane];
    float2 as2 = *(const float2*)&a_s[sl * 2];
    w0 = __expf(leaky02(as2.x + ad2.x));
    w1 = __expf(leaky02(as2.y + ad2.y));
    voff = (uint)sl << 8;
    swA += w0; swB += w1;
  }
  rowA[lane] = make_uint2(voff, __float_as_uint(w0));
  rowB[lane] = make_uint2(voff, __float_as_uint(w1));
}

__device__ __forceinline__ void gather8(const uint4* __restrict__ ebase,
                                        int rem, const char* __restrict__ hb,
                                        unsigned l4, float& acc0, float& acc1) {
  const int nq = (rem + 1) >> 1;
  int q = 0;
  for (; q + 4 <= nq; q += 4) {  // 8 gathers in flight
    uint4 p0 = ebase[q + 0], p1 = ebase[q + 1];
    uint4 p2 = ebase[q + 2], p3 = ebase[q + 3];
    uint va0 = *(const uint*)(hb + (size_t)(p0.x + l4));
    uint vb0 = *(const uint*)(hb + (size_t)(p0.z + l4));
    uint va1 = *(const uint*)(hb + (size_t)(p1.x + l4));
    uint vb1 = *(const uint*)(hb + (size_t)(p1.z + l4));
    uint va2 = *(const uint*)(hb + (size_t)(p2.x + l4));
    uint vb2 = *(const uint*)(hb + (size_t)(p2.z + l4));
    uint va3 = *(const uint*)(hb + (size_t)(p3.x + l4));
    uint vb3 = *(const uint*)(hb + (size_t)(p3.z + l4));
    acc0 = fmaf(__uint_as_float(p0.y), __uint_as_float(va0 << 16), acc0);
    acc1 = fmaf(__uint_as_float(p0.y), __uint_as_float(va0 & 0xffff0000u), acc1);
    acc0 = fmaf(__uint_as_float(p0.w), __uint_as_float(vb0 << 16), acc0);
    acc1 = fmaf(__uint_as_float(p0.w), __uint_as_float(vb0 & 0xffff0000u), acc1);
    acc0 = fmaf(__uint_as_float(p1.y), __uint_as_float(va1 << 16), acc0);
    acc1 = fmaf(__uint_as_float(p1.y), __uint_as_float(va1 & 0xffff0000u), acc1);
    acc0 = fmaf(__uint_as_float(p1.w), __uint_as_float(vb1 << 16), acc0);
    acc1 = fmaf(__uint_as_float(p1.w), __uint_as_float(vb1 & 0xffff0000u), acc1);
    acc0 = fmaf(__uint_as_float(p2.y), __uint_as_float(va2 << 16), acc0);
    acc1 = fmaf(__uint_as_float(p2.y), __uint_as_float(va2 & 0xffff0000u), acc1);
    acc0 = fmaf(__uint_as_float(p2.w), __uint_as_float(vb2 << 16), acc0);
    acc1 = fmaf(__uint_as_float(p2.w), __uint_as_float(vb2 & 0xffff0000u), acc1);
    acc0 = fmaf(__uint_as_float(p3.y), __uint_as_float(va3 << 16), acc0);
    acc1 = fmaf(__uint_as_float(p3.y), __uint_as_float(va3 & 0xffff0000u), acc1);
    acc0 = fmaf(__uint_as_float(p3.w), __uint_as_float(vb3 << 16), acc0);
    acc1 = fmaf(__uint_as_float(p3.w), __uint_as_float(vb3 & 0xffff0000u), acc1);
  }
  for (; q < nq; ++q) {
    uint4 p = ebase[q];
    uint va = *(const uint*)(hb + (size_t)(p.x + l4));
    uint vb = *(const uint*)(hb + (size_t)(p.z + l4));
    acc0 = fmaf(__uint_as_float(p.y), __uint_as_float(va << 16), acc0);
    acc1 = fmaf(__uint_as_float(p.y), __uint_as_float(va & 0xffff0000u), acc1);
    acc0 = fmaf(__uint_as_float(p.w), __uint_as_float(vb << 16), acc0);
    acc1 = fmaf(__uint_as_float(p.w), __uint_as_float(vb & 0xffff0000u), acc1);
  }
}

__device__ __forceinline__ void finish_node(
    int d, float swA, float swB, float acc0, float acc1, float2 ad2,
    const float* __restrict__ a_s, const __hip_bfloat162* __restrict__ h2,
    const float* __restrict__ bias, float* __restrict__ out, int lane) {
  float2 as2 = *(const float2*)&a_s[d * 2];
  float w0 = __expf(leaky02(as2.x + ad2.x));
  float w1 = __expf(leaky02(as2.y + ad2.y));
  swA += w0; swB += w1;
  float av = (lane < 32) ? w0 : w1;
  __hip_bfloat162 hv = h2[(size_t)d * 64 + lane];
  acc0 = fmaf(av, __bfloat162float(hv.x), acc0);
  acc1 = fmaf(av, __bfloat162float(hv.y), acc1);
  float inv = 1.f / (((lane < 32) ? swA : swB) + 1e-16f);
  acc0 *= inv; acc1 *= inv;
  float o0 = acc0 + __shfl_down(acc0, 32, 64);
  float o1 = acc1 + __shfl_down(acc1, 32, 64);
  if (lane < 32) {
    int c = lane * 2;
    *(float2*)&out[(size_t)d * 64 + c] =
        make_float2(0.5f * o0 + bias[c], 0.5f * o1 + bias[c + 1]);
  }
}

// TWO dst nodes per wave, pipelined staging -> overlapped latency chains.
__global__ __launch_bounds__(256) void k_aggr(
    const __hip_bfloat162* __restrict__ h2, const float* __restrict__ a_s,
    const float* __restrict__ a_d, const int* __restrict__ off,
    const int* __restrict__ cnt, const int* __restrict__ csr,
    const float* __restrict__ bias, float* __restrict__ out, int Nn) {
  __shared__ uint2 ewA[8][64];  // 4 KB: [wave*2 + nodeslot]
  __shared__ uint2 ewB[8][64];  // 4 KB
  const int wave = threadIdx.x >> 6;
  const int lane = threadIdx.x & 63;
  const int d0 = blockIdx.x * 8 + wave * 2;
  if (d0 >= Nn) return;
  const int d1 = d0 + 1;
  const bool has1 = (d1 < Nn);
  const int o0 = off[d0], n0 = cnt[d0];
  const int o1 = has1 ? off[d1] : 0;
  const int n1 = has1 ? cnt[d1] : 0;
  const float2 ad20 = *(const float2*)&a_d[d0 * 2];
  const float2 ad21 = has1 ? *(const float2*)&a_d[d1 * 2] : make_float2(0.f, 0.f);
  const char* hb = (const char*)h2;
  const unsigned l4 = lane * 4u;
  const int s0 = wave * 2, s1 = wave * 2 + 1;
  const uint4* eb0 = (lane < 32) ? (const uint4*)&ewA[s0][0]
                                 : (const uint4*)&ewB[s0][0];
  const uint4* eb1 = (lane < 32) ? (const uint4*)&ewA[s1][0]
                                 : (const uint4*)&ewB[s1][0];
  float acc00 = 0.f, acc01 = 0.f, acc10 = 0.f, acc11 = 0.f;
  float swA0 = 0.f, swB0 = 0.f, swA1 = 0.f, swB1 = 0.f;

  const int rem0 = (n0 < 64) ? n0 : 64;
  const int rem1 = (n1 < 64) ? n1 : 64;
  // stage both nodes' first chunks back-to-back: independent load chains
  stage_chunk(csr, a_s, o0, 0, rem0, ad20, lane, ewA[s0], ewB[s0], swA0, swB0);
  stage_chunk(csr, a_s, o1, 0, rem1, ad21, lane, ewA[s1], ewB[s1], swA1, swB1);
  gather8(eb0, rem0, hb, l4, acc00, acc01);
  gather8(eb1, rem1, hb, l4, acc10, acc11);
  // rare tail chunks (deg > 64)
  for (int c = 64; c < n0; c += 64) {
    int rem = n0 - c; if (rem > 64) rem = 64;
    stage_chunk(csr, a_s, o0, c, rem, ad20, lane, ewA[s0], ewB[s0], swA0, swB0);
    gather8(eb0, rem, hb, l4, acc00, acc01);
  }
  for (int c = 64; c < n1; c += 64) {
    int rem = n1 - c; if (rem > 64) rem = 64;
    stage_chunk(csr, a_s, o1, c, rem, ad21, lane, ewA[s1], ewB[s1], swA1, swB1);
    gather8(eb1, rem, hb, l4, acc10, acc11);
  }
  // butterfly-reduce esum partials across the wave (both nodes)
#pragma unroll
  for (int m = 1; m <= 32; m <<= 1) {
    swA0 += __shfl_xor(swA0, m, 64);
    swB0 += __shfl_xor(swB0, m, 64);
    swA1 += __shfl_xor(swA1, m, 64);
    swB1 += __shfl_xor(swB1, m, 64);
  }
  finish_node(d0, swA0, swB0, acc00, acc01, ad20, a_s, h2, bias, out, lane);
  if (has1)
    finish_node(d1, swA1, swB1, acc10, acc11, ad21, a_s, h2, bias, out, lane);
}

extern "C" void kernel_launch(void* const* d_in, const int* in_sizes, int n_in,
                              void* d_out, int out_size, void* d_ws,
                              size_t ws_size, hipStream_t stream) {
  const float* x = (const float*)d_in[0];
  const float* W = (const float*)d_in[1];
  const float* att_s = (const float*)d_in[2];
  const float* att_d = (const float*)d_in[3];
  const float* bias = (const float*)d_in[4];
  const int* ei = (const int*)d_in[5];
  const int Nn = in_sizes[0] / 128;
  const int E = in_sizes[5] / 2;
  const int* src = ei;
  const int* dst = ei + E;
  float* out = (float*)d_out;

  const int nbuck = (Nn + BSZ - 1) >> BSH;          // 391 for N=50000
  const int chunkI = (E + NBLK - 1) / NBLK;         // binsert chunk
  const int ngemm = (Nn + 63) / 64;                 // 782

  // workspace layout
  __hip_bfloat162* h2 = (__hip_bfloat162*)d_ws;     // N*64 bf16x2 (12.8MB)
  float* a_s = (float*)(h2 + (size_t)Nn * 64);      // N*2
  float* a_d = a_s + (size_t)Nn * 2;                // N*2
  int* off = (int*)(a_d + (size_t)Nn * 2);          // N
  int* cnt = off + Nn;                              // N
  int* bhist = cnt + Nn;                            // nbuck*NBLK
  int* cursors = bhist + (size_t)nbuck * NBLK;      // NBLK*nbuck
  int* totals = cursors + (size_t)NBLK * nbuck;     // nbuck
  int* bases = totals + nbuck;                      // nbuck+1
  int* pairs = bases + nbuck + 1;                   // E
  int* csr = pairs + (size_t)E;                     // E

  hipLaunchKernelGGL(k_mega1, dim3(ngemm + NBLK), dim3(256), 0, stream, x, W,
                     att_s, att_d, h2, a_s, a_d, Nn, dst, bhist, E, nbuck,
                     chunkI, ngemm);
  hipLaunchKernelGGL(k_bscan, dim3(nbuck), dim3(NBLK), 0, stream, bhist,
                     cursors, totals, nbuck);
  hipLaunchKernelGGL(k_bbase, dim3(1), dim3(MAXBUCK), 0, stream, totals, bases,
                     nbuck);
  hipLaunchKernelGGL(k_binsert, dim3(NBLK), dim3(TH), 0, stream, src, dst,
                     cursors, bases, pairs, E, nbuck, chunkI);
  hipLaunchKernelGGL(k_bucket, dim3(nbuck), dim3(256), 0, stream, pairs, bases,
                     off, cnt, csr, Nn);
  hipLaunchKernelGGL(k_aggr, dim3((Nn + 7) / 8), dim3(256), 0, stream, h2, a_s,
                     a_d, off, cnt, csr, bias, out, Nn);
}

// Round 11
// 111.265 us; speedup vs baseline: 1.4147x; 1.4147x over previous
//
#include <hip/hip_runtime.h>
#include <hip/hip_bf16.h>

// ---------------------------------------------------------------------------
// GATConv (PyG-style, H=2 heads, C=64, concat=False -> head mean) on gfx950.
// Phases (structure = R7 proven baseline; delta = int8 h with per-row scale):
//   0. k_wa     : WA[k][4] = W @ {att_s,att_d per head}  (logits = x @ WA)
//   1. k_gemm   : h = x@W via bf16 MFMA 16x16x32; a_s/a_d via WA frag (wave3).
//                 Epilogue quantizes h rows to INT8 with per-row fp32 scale
//                 (shfl row-max reduce, no same-address LDS atomic storms;
//                 LDS-transposed coalesced dump). Gather row = 128B = 1 line.
//   2. CSR build via two-level counting sort (no global atomics), as R7.
//   3. k_aggr   : per-dst wave, max-free softmax, single edge sweep.
//                 Head-split LDS staging {voff, w*scl}; esum uses unscaled w
//                 (softmax exact); 1 uint4 = 2 edges; 8 gathers in flight;
//                 per-edge h row read = 128B (int8), decode 2 ch/lane.
// ---------------------------------------------------------------------------

#define NBLK 256   // edge chunks (= threads in k_bscan)
#define TH 512     // threads for bhist/binsert
#define BSH 7      // bucket = dst >> 7
#define BSZ 128    // nodes per bucket
#define MAXBUCK 512
#define PLCAP 8192 // k_bucket LDS pair capacity (32 KB); avg bucket ~4224

typedef __attribute__((ext_vector_type(8))) short bf16x8;
typedef __attribute__((ext_vector_type(4))) float f32x4;

__device__ __forceinline__ ushort f2bf(float f) {
  __hip_bfloat16 b = __float2bfloat16(f);
  union { __hip_bfloat16 b; ushort u; } cv; cv.b = b; return cv.u;
}
__device__ __forceinline__ uint pk2(float a, float b) {
  return (uint)f2bf(a) | ((uint)f2bf(b) << 16);
}
__device__ __forceinline__ float leaky02(float v) {
  return fmaxf(v, 0.2f * v);  // slope 0.2 leaky relu (valid for both signs)
}

// WA[k][0..3] = {W.att_s h0, W.att_s h1, W.att_d h0, W.att_d h1} as bf16
__global__ __launch_bounds__(128) void k_wa(const float* __restrict__ W,
                                            const float* __restrict__ as,
                                            const float* __restrict__ ad,
                                            ushort* __restrict__ wa) {
  const int k = threadIdx.x;  // 0..127
  float s0 = 0.f, s1 = 0.f, d0 = 0.f, d1 = 0.f;
  const float* wr = &W[k * 128];
  for (int c = 0; c < 64; ++c) {
    float w0 = wr[c], w1 = wr[64 + c];
    s0 = fmaf(w0, as[c], s0);
    s1 = fmaf(w1, as[64 + c], s1);
    d0 = fmaf(w0, ad[c], d0);
    d1 = fmaf(w1, ad[64 + c], d1);
  }
  wa[k * 4 + 0] = f2bf(s0);
  wa[k * 4 + 1] = f2bf(s1);
  wa[k * 4 + 2] = f2bf(d0);
  wa[k * 4 + 3] = f2bf(d1);
}

// h = x @ W via bf16 MFMA; fused a_s/a_d via WA fragment (wave 3).
// Epilogue: per-row int8 quantization (scale = rowmax/127).
__global__ __launch_bounds__(256) void k_gemm(
    const float* __restrict__ x, const float* __restrict__ W,
    const ushort* __restrict__ wa, char* __restrict__ hq,
    float* __restrict__ scl, float* __restrict__ a_s,
    float* __restrict__ a_d, int Nn) {
  __shared__ ushort Al[64 * 128];  // 16 KB: x-tile, then reused as Q[64][128]
  __shared__ uint rmaxu[64];
  char* lb = (char*)Al;
  const int wave = threadIdx.x >> 6;
  const int lane = threadIdx.x & 63;
  const int row0 = blockIdx.x * 64;
  const int l15 = lane & 15;
  const int kb = (lane >> 4) * 8;  // k-offset of this lane's frag elements

  if (threadIdx.x < 64) rmaxu[threadIdx.x] = 0u;

  // ---- stage x tile: fp32 -> bf16 LDS, swizzled ----
  {
    const int t = threadIdx.x;
    const int srow = t >> 2, q = t & 3;
    int gr = row0 + srow; gr = (gr < Nn) ? gr : (Nn - 1);
    const float4* xr = (const float4*)&x[(size_t)gr * 128 + q * 32];
#pragma unroll
    for (int i = 0; i < 4; ++i) {
      float4 v0 = xr[2 * i], v1 = xr[2 * i + 1];
      uint4 w;
      w.x = pk2(v0.x, v0.y); w.y = pk2(v0.z, v0.w);
      w.z = pk2(v1.x, v1.y); w.w = pk2(v1.z, v1.w);
      int byte = srow * 256 + ((q * 64 + i * 16) ^ ((srow & 7) << 4));
      *(uint4*)(lb + byte) = w;
    }
  }

  // ---- B fragments (W) in registers: 2 col-tiles x 4 k-steps ----
  bf16x8 bfr[2][4];
#pragma unroll
  for (int c = 0; c < 2; ++c) {
#pragma unroll
    for (int ks = 0; ks < 4; ++ks) {
      const float* wp = &W[(ks * 32 + kb) * 128 + wave * 32 + c * 16 + l15];
      union { bf16x8 v; ushort u[8]; } t;
#pragma unroll
      for (int j = 0; j < 8; ++j) t.u[j] = f2bf(wp[j * 128]);
      bfr[c][ks] = t.v;
    }
  }
  // WA fragment (wave 3 only)
  bf16x8 wafr[4];
  if (wave == 3) {
#pragma unroll
    for (int ks = 0; ks < 4; ++ks) {
      union { bf16x8 v; ushort u[8]; } t;
#pragma unroll
      for (int j = 0; j < 8; ++j)
        t.u[j] = (l15 < 4) ? wa[(ks * 32 + kb + j) * 4 + l15] : (ushort)0;
      wafr[ks] = t.v;
    }
  }

  __syncthreads();

  // ---- MFMA main loop ----
  f32x4 acc[4][2];
  f32x4 accwa[4];
#pragma unroll
  for (int r = 0; r < 4; ++r) {
    acc[r][0] = (f32x4){0.f, 0.f, 0.f, 0.f};
    acc[r][1] = (f32x4){0.f, 0.f, 0.f, 0.f};
    accwa[r] = (f32x4){0.f, 0.f, 0.f, 0.f};
  }
#pragma unroll
  for (int ks = 0; ks < 4; ++ks) {
    bf16x8 af[4];
#pragma unroll
    for (int r = 0; r < 4; ++r) {
      int row = r * 16 + l15;
      int byte = row * 256 + ((ks * 64 + (lane >> 4) * 16) ^ ((row & 7) << 4));
      uint4 v = *(const uint4*)(lb + byte);
      union { uint4 q; bf16x8 v; } cv; cv.q = v;
      af[r] = cv.v;
    }
#pragma unroll
    for (int r = 0; r < 4; ++r) {
      acc[r][0] = __builtin_amdgcn_mfma_f32_16x16x32_bf16(af[r], bfr[0][ks],
                                                          acc[r][0], 0, 0, 0);
      acc[r][1] = __builtin_amdgcn_mfma_f32_16x16x32_bf16(af[r], bfr[1][ks],
                                                          acc[r][1], 0, 0, 0);
    }
    if (wave == 3) {
#pragma unroll
      for (int r = 0; r < 4; ++r)
        accwa[r] = __builtin_amdgcn_mfma_f32_16x16x32_bf16(af[r], wafr[ks],
                                                           accwa[r], 0, 0, 0);
    }
  }

  // ---- row-max: per-thread |acc| max, shfl-reduce over l15 group ----
  const int rbase = (lane >> 4) * 4;
  float rm[4][4];
#pragma unroll
  for (int r = 0; r < 4; ++r)
#pragma unroll
    for (int i = 0; i < 4; ++i)
      rm[r][i] = fmaxf(fabsf(acc[r][0][i]), fabsf(acc[r][1][i]));
#pragma unroll
  for (int m = 1; m <= 8; m <<= 1) {
#pragma unroll
    for (int r = 0; r < 4; ++r)
#pragma unroll
      for (int i = 0; i < 4; ++i)
        rm[r][i] = fmaxf(rm[r][i], __shfl_xor(rm[r][i], m, 64));
  }
  __syncthreads();  // all MFMA LDS reads done; Al reusable as Q
  if (l15 == 0) {
#pragma unroll
    for (int r = 0; r < 4; ++r)
#pragma unroll
      for (int i = 0; i < 4; ++i)
        atomicMax(&rmaxu[r * 16 + rbase + i], __float_as_uint(rm[r][i]));
  }
  __syncthreads();

  // ---- quantize into LDS byte tile Q[64][128], write scl ----
  char* Q = (char*)Al;
#pragma unroll
  for (int r = 0; r < 4; ++r) {
#pragma unroll
    for (int i = 0; i < 4; ++i) {
      const int lrow = r * 16 + rbase + i;
      const float inv = 127.f / fmaxf(__uint_as_float(rmaxu[lrow]), 1e-20f);
#pragma unroll
      for (int c = 0; c < 2; ++c) {
        const int col = wave * 32 + c * 16 + l15;
        int qv = __float2int_rn(acc[r][c][i] * inv);
        qv = (qv > 127) ? 127 : ((qv < -127) ? -127 : qv);
        Q[lrow * 128 + col] = (char)qv;
      }
    }
  }
  if (threadIdx.x < 64) {
    const int grow = row0 + threadIdx.x;
    if (grow < Nn)
      scl[grow] = __uint_as_float(rmaxu[threadIdx.x]) * (1.f / 127.f);
  }
  // ---- store a_s / a_d from WA accumulators ----
  if (wave == 3) {
#pragma unroll
    for (int r = 0; r < 4; ++r) {
#pragma unroll
      for (int i = 0; i < 4; ++i) {
        int grow = row0 + r * 16 + rbase + i;
        if (grow < Nn) {
          float v = accwa[r][i];
          if (l15 < 2) a_s[grow * 2 + l15] = v;
          else if (l15 < 4) a_d[grow * 2 + (l15 - 2)] = v;
        }
      }
    }
  }
  __syncthreads();
  // ---- coalesced dump Q -> hq ----
#pragma unroll
  for (int k = 0; k < 2; ++k) {
    const int idx = threadIdx.x * 2 + k;  // 0..511 = 64 rows x 8 chunks
    const int row = idx >> 3;
    const int col = (idx & 7) * 16;
    uint4 v = *(const uint4*)(Q + row * 128 + col);
    if (row0 + row < Nn)
      *(uint4*)&hq[(size_t)(row0 + row) * 128 + col] = v;
  }
}

// per-chunk LDS histogram over buckets -> bhist[bucket][chunk]
__global__ __launch_bounds__(TH) void k_bhist(const int* __restrict__ dst,
                                              int* __restrict__ bhist, int E,
                                              int nbuck, int chunk) {
  __shared__ int hl[MAXBUCK];
  for (int i = threadIdx.x; i < nbuck; i += TH) hl[i] = 0;
  __syncthreads();
  const int s = blockIdx.x * chunk;
  const int e = (s + chunk < E) ? s + chunk : E;
  for (int i = s + threadIdx.x; i < e; i += TH)
    atomicAdd(&hl[dst[i] >> BSH], 1);
  __syncthreads();
  for (int b = threadIdx.x; b < nbuck; b += TH)
    bhist[b * NBLK + blockIdx.x] = hl[b];
}

// per bucket: exclusive scan over chunks -> raw cursors; write bucket total
__global__ __launch_bounds__(NBLK) void k_bscan(const int* __restrict__ bhist,
                                                int* __restrict__ cursors,
                                                int* __restrict__ totals,
                                                int nbuck) {
  __shared__ int tmp[NBLK];
  const int b = blockIdx.x;
  const int t = threadIdx.x;
  const int v = bhist[b * NBLK + t];
  tmp[t] = v;
  __syncthreads();
  for (int d = 1; d < NBLK; d <<= 1) {
    int add = (t >= d) ? tmp[t - d] : 0;
    __syncthreads();
    tmp[t] += add;
    __syncthreads();
  }
  cursors[t * nbuck + b] = tmp[t] - v;  // raw (no base)
  if (t == NBLK - 1) totals[b] = tmp[t];
}

// exclusive scan of bucket totals -> bases[0..nbuck]
__global__ __launch_bounds__(MAXBUCK) void k_bbase(const int* __restrict__ totals,
                                                   int* __restrict__ bases,
                                                   int nbuck) {
  __shared__ int tmp[MAXBUCK];
  const int t = threadIdx.x;
  const int v = (t < nbuck) ? totals[t] : 0;
  tmp[t] = v;
  __syncthreads();
  for (int d = 1; d < MAXBUCK; d <<= 1) {
    int add = (t >= d) ? tmp[t - d] : 0;
    __syncthreads();
    tmp[t] += add;
    __syncthreads();
  }
  if (t < nbuck) bases[t] = tmp[t] - v;
  if (t == nbuck - 1) bases[nbuck] = tmp[t];
}

// scatter packed (local_dst<<16 | src) into bucket-grouped pairs array
__global__ __launch_bounds__(TH) void k_binsert(
    const int* __restrict__ src, const int* __restrict__ dst,
    const int* __restrict__ cursors, const int* __restrict__ bases,
    int* __restrict__ pairs, int E, int nbuck, int chunk) {
  __shared__ int cur[MAXBUCK];
  for (int i = threadIdx.x; i < nbuck; i += TH)
    cur[i] = cursors[blockIdx.x * nbuck + i] + bases[i];
  __syncthreads();
  const int s = blockIdx.x * chunk;
  const int e = (s + chunk < E) ? s + chunk : E;
  for (int i = s + threadIdx.x; i < e; i += TH) {
    const int d = dst[i];
    const int b = d >> BSH;
    const int p = atomicAdd(&cur[b], 1);
    pairs[p] = ((d & (BSZ - 1)) << 16) | src[i];
  }
}

// per bucket: single-pass (pairs staged in LDS): count+scan -> off/cnt, then
// LDS-sourced scatter into csr. Fallback to two global passes if oversized.
__global__ __launch_bounds__(256) void k_bucket(
    const int* __restrict__ pairs, const int* __restrict__ bases,
    int* __restrict__ off, int* __restrict__ cnt, int* __restrict__ csr,
    int Nn) {
  __shared__ int pl[PLCAP];  // 32 KB
  __shared__ int cl[BSZ];
  __shared__ int tmp[BSZ];
  __shared__ int cu[BSZ];
  const int b = blockIdx.x;
  const int t = threadIdx.x;
  const int n0 = b << BSH;
  if (t < BSZ) cl[t] = 0;
  __syncthreads();
  const int s = bases[b], e = bases[b + 1];
  const int len = e - s;
  const bool fit = (len <= PLCAP);
  if (fit) {
    for (int i = t; i < len; i += 256) {
      int pv = pairs[s + i];
      pl[i] = pv;
      atomicAdd(&cl[pv >> 16], 1);
    }
  } else {
    for (int i = s + t; i < e; i += 256) atomicAdd(&cl[pairs[i] >> 16], 1);
  }
  __syncthreads();
  int v = 0;
  if (t < BSZ) { v = cl[t]; tmp[t] = v; }
  __syncthreads();
  for (int d = 1; d < BSZ; d <<= 1) {
    int add = (t < BSZ && t >= d) ? tmp[t - d] : 0;
    __syncthreads();
    if (t < BSZ) tmp[t] += add;
    __syncthreads();
  }
  if (t < BSZ) {
    const int excl = tmp[t] - v;
    cu[t] = s + excl;
    const int node = n0 + t;
    if (node < Nn) { off[node] = s + excl; cnt[node] = v; }
  }
  __syncthreads();
  if (fit) {
    for (int i = t; i < len; i += 256) {
      const int pv = pl[i];
      const int p = atomicAdd(&cu[pv >> 16], 1);
      csr[p] = pv & 0xffff;
    }
  } else {
    for (int i = s + t; i < e; i += 256) {
      const int pv = pairs[i];
      const int p = atomicAdd(&cu[pv >> 16], 1);
      csr[p] = pv & 0xffff;
    }
  }
}

// One wave per destination node. Max-free softmax, single edge sweep.
// Head-split staging: ewA = {voff, w0*scl}, ewB = {voff, w1*scl}; esum from
// unscaled w (softmax exact). h rows are int8 (128B = 1 line), scale folded
// into the staged weight.
__global__ __launch_bounds__(256) void k_aggr(
    const char* __restrict__ hq, const float* __restrict__ scl,
    const float* __restrict__ a_s, const float* __restrict__ a_d,
    const int* __restrict__ off, const int* __restrict__ cnt,
    const int* __restrict__ csr, const float* __restrict__ bias,
    float* __restrict__ out, int Nn) {
  __shared__ uint2 ewA[4][64];  // 2 KB
  __shared__ uint2 ewB[4][64];  // 2 KB
  const int wave = threadIdx.x >> 6;
  const int lane = threadIdx.x & 63;
  const int d = blockIdx.x * 4 + wave;
  if (d >= Nn) return;
  const int o = off[d];
  const int deg = cnt[d];
  const float2 ad2 = *(const float2*)&a_d[d * 2];
  const unsigned l2 = lane * 2u;  // byte offset of this lane's 2 int8 channels
  const uint4* ebase = (lane < 32) ? (const uint4*)&ewA[wave][0]
                                   : (const uint4*)&ewB[wave][0];
  float acc0 = 0.f, acc1 = 0.f;   // this lane's 2 channels
  float sw0 = 0.f, sw1 = 0.f;     // per-lane partial esum (head0, head1)

  for (int c = 0; c < deg; c += 64) {
    int rem = deg - c; if (rem > 64) rem = 64;
    {
      unsigned voff = 0; float w0 = 0.f, w1 = 0.f, ws0 = 0.f, ws1 = 0.f;
      if (lane < rem) {
        int sl = csr[o + c + lane];
        float2 as2 = *(const float2*)&a_s[sl * 2];
        w0 = __expf(leaky02(as2.x + ad2.x));
        w1 = __expf(leaky02(as2.y + ad2.y));
        float s = scl[sl];
        voff = (unsigned)sl << 7;  // byte offset of hq row (128 B/row)
        sw0 += w0; sw1 += w1;
        ws0 = w0 * s; ws1 = w1 * s;
      }
      ewA[wave][lane] = make_uint2(voff, __float_as_uint(ws0));
      ewB[wave][lane] = make_uint2(voff, __float_as_uint(ws1));
    }
    // one uint4 from LDS = TWO edges {voffA, wsA, voffB, wsB}
    const int nq = (rem + 1) >> 1;
    int q = 0;
    for (; q + 4 <= nq; q += 4) {  // 8 gathers in flight
      uint4 p0 = ebase[q + 0], p1 = ebase[q + 1];
      uint4 p2 = ebase[q + 2], p3 = ebase[q + 3];
      ushort a0 = *(const ushort*)(hq + (size_t)(p0.x + l2));
      ushort b0 = *(const ushort*)(hq + (size_t)(p0.z + l2));
      ushort a1 = *(const ushort*)(hq + (size_t)(p1.x + l2));
      ushort b1 = *(const ushort*)(hq + (size_t)(p1.z + l2));
      ushort a2 = *(const ushort*)(hq + (size_t)(p2.x + l2));
      ushort b2 = *(const ushort*)(hq + (size_t)(p2.z + l2));
      ushort a3 = *(const ushort*)(hq + (size_t)(p3.x + l2));
      ushort b3 = *(const ushort*)(hq + (size_t)(p3.z + l2));
      float wA0 = __uint_as_float(p0.y), wB0 = __uint_as_float(p0.w);
      float wA1 = __uint_as_float(p1.y), wB1 = __uint_as_float(p1.w);
      float wA2 = __uint_as_float(p2.y), wB2 = __uint_as_float(p2.w);
      float wA3 = __uint_as_float(p3.y), wB3 = __uint_as_float(p3.w);
      acc0 = fmaf(wA0, (float)(signed char)(a0 & 0xff), acc0);
      acc1 = fmaf(wA0, (float)(signed char)(a0 >> 8), acc1);
      acc0 = fmaf(wB0, (float)(signed char)(b0 & 0xff), acc0);
      acc1 = fmaf(wB0, (float)(signed char)(b0 >> 8), acc1);
      acc0 = fmaf(wA1, (float)(signed char)(a1 & 0xff), acc0);
      acc1 = fmaf(wA1, (float)(signed char)(a1 >> 8), acc1);
      acc0 = fmaf(wB1, (float)(signed char)(b1 & 0xff), acc0);
      acc1 = fmaf(wB1, (float)(signed char)(b1 >> 8), acc1);
      acc0 = fmaf(wA2, (float)(signed char)(a2 & 0xff), acc0);
      acc1 = fmaf(wA2, (float)(signed char)(a2 >> 8), acc1);
      acc0 = fmaf(wB2, (float)(signed char)(b2 & 0xff), acc0);
      acc1 = fmaf(wB2, (float)(signed char)(b2 >> 8), acc1);
      acc0 = fmaf(wA3, (float)(signed char)(a3 & 0xff), acc0);
      acc1 = fmaf(wA3, (float)(signed char)(a3 >> 8), acc1);
      acc0 = fmaf(wB3, (float)(signed char)(b3 & 0xff), acc0);
      acc1 = fmaf(wB3, (float)(signed char)(b3 >> 8), acc1);
    }
    for (; q < nq; ++q) {
      uint4 p = ebase[q];
      ushort va = *(const ushort*)(hq + (size_t)(p.x + l2));
      ushort vb = *(const ushort*)(hq + (size_t)(p.z + l2));
      float wA = __uint_as_float(p.y), wB = __uint_as_float(p.w);
      acc0 = fmaf(wA, (float)(signed char)(va & 0xff), acc0);
      acc1 = fmaf(wA, (float)(signed char)(va >> 8), acc1);
      acc0 = fmaf(wB, (float)(signed char)(vb & 0xff), acc0);
      acc1 = fmaf(wB, (float)(signed char)(vb >> 8), acc1);
    }
  }
  // butterfly-reduce per-lane esum partials across the wave
#pragma unroll
  for (int msk = 1; msk <= 32; msk <<= 1) {
    sw0 += __shfl_xor(sw0, msk, 64);
    sw1 += __shfl_xor(sw1, msk, 64);
  }
  // self loop
  {
    float2 as2 = *(const float2*)&a_s[d * 2];
    float w0 = __expf(leaky02(as2.x + ad2.x));
    float w1 = __expf(leaky02(as2.y + ad2.y));
    sw0 += w0; sw1 += w1;
    float av = ((lane < 32) ? w0 : w1) * scl[d];
    ushort v = *(const ushort*)(hq + ((size_t)d << 7) + l2);
    acc0 = fmaf(av, (float)(signed char)(v & 0xff), acc0);
    acc1 = fmaf(av, (float)(signed char)(v >> 8), acc1);
  }
  const float invsel = 1.f / (((lane < 32) ? sw0 : sw1) + 1e-16f);
  acc0 *= invsel; acc1 *= invsel;
  // head mean: lane l (<32, head0 ch 2l,2l+1) + lane l+32 (head1 ch 2l,2l+1)
  float o0 = acc0 + __shfl_down(acc0, 32, 64);
  float o1 = acc1 + __shfl_down(acc1, 32, 64);
  if (lane < 32) {
    int c = lane * 2;
    float2 res = make_float2(0.5f * o0 + bias[c], 0.5f * o1 + bias[c + 1]);
    *(float2*)&out[(size_t)d * 64 + c] = res;
  }
}

extern "C" void kernel_launch(void* const* d_in, const int* in_sizes, int n_in,
                              void* d_out, int out_size, void* d_ws,
                              size_t ws_size, hipStream_t stream) {
  const float* x = (const float*)d_in[0];
  const float* W = (const float*)d_in[1];
  const float* att_s = (const float*)d_in[2];
  const float* att_d = (const float*)d_in[3];
  const float* bias = (const float*)d_in[4];
  const int* ei = (const int*)d_in[5];
  const int Nn = in_sizes[0] / 128;
  const int E = in_sizes[5] / 2;
  const int* src = ei;
  const int* dst = ei + E;
  float* out = (float*)d_out;

  const int nbuck = (Nn + BSZ - 1) >> BSH;          // 391 for N=50000
  const int chunk = (E + NBLK - 1) / NBLK;          // 6250 for E=1.6M

  // workspace layout
  char* hq = (char*)d_ws;                           // N*128 int8 (6.4MB)
  float* scl = (float*)(hq + (size_t)Nn * 128);     // N
  float* a_s = scl + Nn;                            // N*2
  float* a_d = a_s + (size_t)Nn * 2;                // N*2
  int* off = (int*)(a_d + (size_t)Nn * 2);          // N
  int* cnt = off + Nn;                              // N
  int* bhist = cnt + Nn;                            // nbuck*NBLK
  int* cursors = bhist + (size_t)nbuck * NBLK;      // NBLK*nbuck
  int* totals = cursors + (size_t)NBLK * nbuck;     // nbuck
  int* bases = totals + nbuck;                      // nbuck+1
  ushort* wa = (ushort*)(bases + nbuck + 1);        // 512 bf16
  int* pairs = (int*)(wa + 512);                    // E
  int* csr = pairs + (size_t)E;                     // E

  hipLaunchKernelGGL(k_wa, dim3(1), dim3(128), 0, stream, W, att_s, att_d, wa);
  hipLaunchKernelGGL(k_gemm, dim3((Nn + 63) / 64), dim3(256), 0, stream, x, W,
                     wa, hq, scl, a_s, a_d, Nn);
  hipLaunchKernelGGL(k_bhist, dim3(NBLK), dim3(TH), 0, stream, dst, bhist, E,
                     nbuck, chunk);
  hipLaunchKernelGGL(k_bscan, dim3(nbuck), dim3(NBLK), 0, stream, bhist,
                     cursors, totals, nbuck);
  hipLaunchKernelGGL(k_bbase, dim3(1), dim3(MAXBUCK), 0, stream, totals, bases,
                     nbuck);
  hipLaunchKernelGGL(k_binsert, dim3(NBLK), dim3(TH), 0, stream, src, dst,
                     cursors, bases, pairs, E, nbuck, chunk);
  hipLaunchKernelGGL(k_bucket, dim3(nbuck), dim3(256), 0, stream, pairs, bases,
                     off, cnt, csr, Nn);
  hipLaunchKernelGGL(k_aggr, dim3((Nn + 3) / 4), dim3(256), 0, stream, hq, scl,
                     a_s, a_d, off, cnt, csr, bias, out, Nn);
}